// Round 8
// baseline (11060.304 us; speedup 1.0000x reference)
//
#include <hip/hip_runtime.h>
#include <math.h>

#define HID 1024
#define SEQ 4096
#define NWG 64        // 64 WGs x 256 thr; co-resident, proven config
#define BT  8         // t-tile for the U GEMM

typedef float v4f __attribute__((ext_vector_type(4)));

// ---------------------------------------------------------------------------
// Phase 1+2 fused: embedding gather + L2 normalize + U = emb @ W_hi^T + b
// (unchanged — proven, ~0.7 ms)
// ---------------------------------------------------------------------------
__global__ void __launch_bounds__(256) embed_gemm(
    const int* __restrict__ src, const float* __restrict__ W,
    const float* __restrict__ Whi, const float* __restrict__ bias,
    float* __restrict__ U) {
  __shared__ float4 se[BT][256];
  __shared__ float  sw[BT][4];

  const int tid  = threadIdx.x;
  const int wv   = tid >> 6;
  const int lane = tid & 63;
  const int t0   = blockIdx.x * BT;

  #pragma unroll
  for (int i = 0; i < BT; i++) {
    const int idx = src[t0 + i];
    float4 v = ((const float4*)(W + (size_t)idx * HID))[tid];
    se[i][tid] = v;
    float ss = v.x*v.x + v.y*v.y + v.z*v.z + v.w*v.w;
    ss += __shfl_xor(ss, 1);  ss += __shfl_xor(ss, 2);  ss += __shfl_xor(ss, 4);
    ss += __shfl_xor(ss, 8);  ss += __shfl_xor(ss, 16); ss += __shfl_xor(ss, 32);
    if (lane == 0) sw[i][wv] = ss;
  }
  __syncthreads();

  float inv_norm[BT];
  #pragma unroll
  for (int i = 0; i < BT; i++) {
    float n = sw[i][0] + sw[i][1] + sw[i][2] + sw[i][3];
    inv_norm[i] = 1.0f / fmaxf(sqrtf(n), 1e-12f);
  }

  float acc[BT][4];
  #pragma unroll
  for (int i = 0; i < BT; i++)
    #pragma unroll
    for (int q = 0; q < 4; q++) acc[i][q] = 0.0f;

  for (int k4 = 0; k4 < HID / 4; k4++) {
    float4 wr[4];
    #pragma unroll
    for (int q = 0; q < 4; q++)
      wr[q] = *(const float4*)(Whi + (size_t)(tid + q * 256) * HID + k4 * 4);
    #pragma unroll
    for (int i = 0; i < BT; i++) {
      float4 e = se[i][k4];
      #pragma unroll
      for (int q = 0; q < 4; q++)
        acc[i][q] += wr[q].x*e.x + wr[q].y*e.y + wr[q].z*e.z + wr[q].w*e.w;
    }
  }

  #pragma unroll
  for (int i = 0; i < BT; i++) {
    #pragma unroll
    for (int q = 0; q < 4; q++) {
      const int j = tid + q * 256;
      U[(size_t)(t0 + i) * HID + j] = acc[i][q] * inv_norm[i] + bias[j];
    }
  }
}

// ---------------------------------------------------------------------------
// Pipelined dual-set poll + LDS relay (wave 0 only).
// SOUNDNESS: the whole loop is ONE asm block; sets A (v[32:47]) and B
// (v[48:63]) live in pinned, clobbered physical VGPRs, so the in-flight set
// can only ever land in block-owned registers; every exit path does
// s_waitcnt vmcnt(0) before leaving. vmcnt(4) retires the older set while
// the newer is in flight (in-order retirement); stray prior stores/loads are
// absorbed by the first wait (it only waits longer, never less).
// Check per set: max |x - Bc| over the lane's 16 dwords < 1.5 on all lanes.
// Valid data in [Bc-1,Bc+1]; other-gen window, zeros, 0xAA poison all fail.
// ---------------------------------------------------------------------------
__device__ __forceinline__ void poll_relay(const float* slotbase, float Bc,
                                           float* dst_lds, int lane,
                                           int* sdead) {
  const float* src = slotbase + 4 * lane;
  float f0, f1, f2, f3, f4, f5, f6, f7, f8, f9, fa, fb, fc, fd, fe, ff;
  unsigned df;

#define CHK_SET(BASE0)                                                        \
      "v_subrev_f32 v28, %[bc], v" #BASE0 "\n\t"

  asm volatile(
    // prologue: issue A then B
    "global_load_dwordx4 v[32:35], %[src], off sc0 sc1\n\t"
    "global_load_dwordx4 v[36:39], %[src], off offset:1024 sc0 sc1\n\t"
    "global_load_dwordx4 v[40:43], %[src], off offset:2048 sc0 sc1\n\t"
    "global_load_dwordx4 v[44:47], %[src], off offset:3072 sc0 sc1\n\t"
    "global_load_dwordx4 v[48:51], %[src], off sc0 sc1\n\t"
    "global_load_dwordx4 v[52:55], %[src], off offset:1024 sc0 sc1\n\t"
    "global_load_dwordx4 v[56:59], %[src], off offset:2048 sc0 sc1\n\t"
    "global_load_dwordx4 v[60:63], %[src], off offset:3072 sc0 sc1\n\t"
    "s_mov_b32 %[df], 0\n\t"
  "Lpoll%=:\n\t"
    "s_add_u32 %[df], %[df], 1\n\t"
    "s_cmp_gt_u32 %[df], 0x40000\n\t"
    "s_cbranch_scc1 Lbail%=\n\t"
    // ---- wait A (older set; first pass also drains stray stores) ----
    "s_waitcnt vmcnt(4)\n\t"
    // ---- check A: v32..v47 ----
    "v_subrev_f32 v28, %[bc], v32\n\t"
    "v_subrev_f32 v29, %[bc], v33\n\t"
    "v_subrev_f32 v30, %[bc], v34\n\t"
    "v_max3_f32 v31, |v28|, |v29|, |v30|\n\t"
    "v_subrev_f32 v28, %[bc], v35\n\t"
    "v_subrev_f32 v29, %[bc], v36\n\t"
    "v_subrev_f32 v30, %[bc], v37\n\t"
    "v_max3_f32 v28, |v28|, |v29|, |v30|\n\t"
    "v_max_f32 v31, v31, v28\n\t"
    "v_subrev_f32 v28, %[bc], v38\n\t"
    "v_subrev_f32 v29, %[bc], v39\n\t"
    "v_subrev_f32 v30, %[bc], v40\n\t"
    "v_max3_f32 v28, |v28|, |v29|, |v30|\n\t"
    "v_max_f32 v31, v31, v28\n\t"
    "v_subrev_f32 v28, %[bc], v41\n\t"
    "v_subrev_f32 v29, %[bc], v42\n\t"
    "v_subrev_f32 v30, %[bc], v43\n\t"
    "v_max3_f32 v28, |v28|, |v29|, |v30|\n\t"
    "v_max_f32 v31, v31, v28\n\t"
    "v_subrev_f32 v28, %[bc], v44\n\t"
    "v_subrev_f32 v29, %[bc], v45\n\t"
    "v_subrev_f32 v30, %[bc], v46\n\t"
    "v_max3_f32 v28, |v28|, |v29|, |v30|\n\t"
    "v_max_f32 v31, v31, v28\n\t"
    "v_subrev_f32 v28, %[bc], v47\n\t"
    "v_max_f32 v31, v31, |v28|\n\t"
    "v_cmp_le_f32 vcc, 1.5, v31\n\t"
    "s_cbranch_vccz LdoneA%=\n\t"
    // ---- reissue A (B still in flight) ----
    "global_load_dwordx4 v[32:35], %[src], off sc0 sc1\n\t"
    "global_load_dwordx4 v[36:39], %[src], off offset:1024 sc0 sc1\n\t"
    "global_load_dwordx4 v[40:43], %[src], off offset:2048 sc0 sc1\n\t"
    "global_load_dwordx4 v[44:47], %[src], off offset:3072 sc0 sc1\n\t"
    // ---- wait B ----
    "s_waitcnt vmcnt(4)\n\t"
    // ---- check B: v48..v63 ----
    "v_subrev_f32 v28, %[bc], v48\n\t"
    "v_subrev_f32 v29, %[bc], v49\n\t"
    "v_subrev_f32 v30, %[bc], v50\n\t"
    "v_max3_f32 v31, |v28|, |v29|, |v30|\n\t"
    "v_subrev_f32 v28, %[bc], v51\n\t"
    "v_subrev_f32 v29, %[bc], v52\n\t"
    "v_subrev_f32 v30, %[bc], v53\n\t"
    "v_max3_f32 v28, |v28|, |v29|, |v30|\n\t"
    "v_max_f32 v31, v31, v28\n\t"
    "v_subrev_f32 v28, %[bc], v54\n\t"
    "v_subrev_f32 v29, %[bc], v55\n\t"
    "v_subrev_f32 v30, %[bc], v56\n\t"
    "v_max3_f32 v28, |v28|, |v29|, |v30|\n\t"
    "v_max_f32 v31, v31, v28\n\t"
    "v_subrev_f32 v28, %[bc], v57\n\t"
    "v_subrev_f32 v29, %[bc], v58\n\t"
    "v_subrev_f32 v30, %[bc], v59\n\t"
    "v_max3_f32 v28, |v28|, |v29|, |v30|\n\t"
    "v_max_f32 v31, v31, v28\n\t"
    "v_subrev_f32 v28, %[bc], v60\n\t"
    "v_subrev_f32 v29, %[bc], v61\n\t"
    "v_subrev_f32 v30, %[bc], v62\n\t"
    "v_max3_f32 v28, |v28|, |v29|, |v30|\n\t"
    "v_max_f32 v31, v31, v28\n\t"
    "v_subrev_f32 v28, %[bc], v63\n\t"
    "v_max_f32 v31, v31, |v28|\n\t"
    "v_cmp_le_f32 vcc, 1.5, v31\n\t"
    "s_cbranch_vccz LdoneB%=\n\t"
    // ---- reissue B (A in flight) ----
    "global_load_dwordx4 v[48:51], %[src], off sc0 sc1\n\t"
    "global_load_dwordx4 v[52:55], %[src], off offset:1024 sc0 sc1\n\t"
    "global_load_dwordx4 v[56:59], %[src], off offset:2048 sc0 sc1\n\t"
    "global_load_dwordx4 v[60:63], %[src], off offset:3072 sc0 sc1\n\t"
    "s_branch Lpoll%=\n\t"
  "LdoneB%=:\n\t"
    "s_waitcnt vmcnt(0)\n\t"          // stray A loads land in v[32:47] (dead)
    "v_mov_b32 v32, v48\n\t"  "v_mov_b32 v33, v49\n\t"
    "v_mov_b32 v34, v50\n\t"  "v_mov_b32 v35, v51\n\t"
    "v_mov_b32 v36, v52\n\t"  "v_mov_b32 v37, v53\n\t"
    "v_mov_b32 v38, v54\n\t"  "v_mov_b32 v39, v55\n\t"
    "v_mov_b32 v40, v56\n\t"  "v_mov_b32 v41, v57\n\t"
    "v_mov_b32 v42, v58\n\t"  "v_mov_b32 v43, v59\n\t"
    "v_mov_b32 v44, v60\n\t"  "v_mov_b32 v45, v61\n\t"
    "v_mov_b32 v46, v62\n\t"  "v_mov_b32 v47, v63\n\t"
    "s_branch Lgood%=\n\t"
  "LdoneA%=:\n\t"
    "s_waitcnt vmcnt(0)\n\t"          // stray B loads land in v[48:63] (dead)
  "Lgood%=:\n\t"
    "s_mov_b32 %[df], 0\n\t"
    "s_branch Lend%=\n\t"
  "Lbail%=:\n\t"
    "s_waitcnt vmcnt(0)\n\t"
    "s_mov_b32 %[df], 1\n\t"
  "Lend%=:\n\t"
    "v_mov_b32 %[f0], v32\n\t"  "v_mov_b32 %[f1], v33\n\t"
    "v_mov_b32 %[f2], v34\n\t"  "v_mov_b32 %[f3], v35\n\t"
    "v_mov_b32 %[f4], v36\n\t"  "v_mov_b32 %[f5], v37\n\t"
    "v_mov_b32 %[f6], v38\n\t"  "v_mov_b32 %[f7], v39\n\t"
    "v_mov_b32 %[f8], v40\n\t"  "v_mov_b32 %[f9], v41\n\t"
    "v_mov_b32 %[fa], v42\n\t"  "v_mov_b32 %[fb], v43\n\t"
    "v_mov_b32 %[fc], v44\n\t"  "v_mov_b32 %[fd], v45\n\t"
    "v_mov_b32 %[fe], v46\n\t"  "v_mov_b32 %[ff], v47"
    : [f0]"=v"(f0), [f1]"=v"(f1), [f2]"=v"(f2), [f3]"=v"(f3),
      [f4]"=v"(f4), [f5]"=v"(f5), [f6]"=v"(f6), [f7]"=v"(f7),
      [f8]"=v"(f8), [f9]"=v"(f9), [fa]"=v"(fa), [fb]"=v"(fb),
      [fc]"=v"(fc), [fd]"=v"(fd), [fe]"=v"(fe), [ff]"=v"(ff),
      [df]"=&s"(df)
    : [src]"v"(src), [bc]"v"(Bc)
    : "v28","v29","v30","v31",
      "v32","v33","v34","v35","v36","v37","v38","v39",
      "v40","v41","v42","v43","v44","v45","v46","v47",
      "v48","v49","v50","v51","v52","v53","v54","v55",
      "v56","v57","v58","v59","v60","v61","v62","v63",
      "vcc","scc","memory");
#undef CHK_SET

  if (df) *sdead = 1;
  v4f o0 = {f0, f1, f2, f3};  o0 -= Bc;
  v4f o1 = {f4, f5, f6, f7};  o1 -= Bc;
  v4f o2 = {f8, f9, fa, fb};  o2 -= Bc;
  v4f o3 = {fc, fd, fe, ff};  o3 -= Bc;
  *(v4f*)(dst_lds +   0 + 4 * lane) = o0;   // ds_write_b128, conflict-free
  *(v4f*)(dst_lds + 256 + 4 * lane) = o1;
  *(v4f*)(dst_lds + 512 + 4 * lane) = o2;
  *(v4f*)(dst_lds + 768 + 4 * lane) = o3;
}

// fast tanh: 1 - 2/(e^{2x}+1); clamp avoids inf; err ~1e-6 << 1.58e-3 thr
__device__ __forceinline__ float tanh_fast(float x) {
  x = fminf(fmaxf(x, -15.0f), 15.0f);
  float e = __expf(2.0f * x);
  return 1.0f - 2.0f * __builtin_amdgcn_rcpf(e + 1.0f);
}

// ---------------------------------------------------------------------------
// Phase 3: persistent RNN, LLC data-as-flag sync, WG-level pipelined poller
// + LDS relay (structure proven in R7; poll loop now dual-set pipelined).
// ---------------------------------------------------------------------------
__global__ void __launch_bounds__(256) rnn_seq(
    const float* __restrict__ Whh, const float* __restrict__ U,
    const float* __restrict__ h0, float* __restrict__ out,
    float* __restrict__ hbuf) {
  __shared__ float hsh[2][HID];
  __shared__ int   sdead;

  const int tid   = threadIdx.x;
  const int lane  = tid & 63;
  const int w     = tid >> 6;
  const int b     = blockIdx.x;
  const int r0    = b * 16;              // WG's 16 rows
  const int rw    = r0 + w * 4;          // wave's 4 rows
  const int myrow = rw + (lane & 3);     // row this lane finalizes u for

  if (tid == 0) sdead = 0;

  // init publish (wave 0 lanes 0..15): rows r0..r0+15 into slot 0, base 2.0
  if (tid < 16) {
    float rv = h0[r0 + tid];
    out[r0 + tid] = rv;
    float tv = rv + 2.0f;
    const float* dst = hbuf + r0 + tid;
    asm volatile("global_store_dword %0, %1, off sc0 sc1"
                 :: "v"(dst), "v"(tv) : "memory");
  }

  // W_hh fragments: wreg[r][c] = Whh[rw+r][c*256 + 4l .. +3]
  v4f wreg[4][4];
  #pragma unroll
  for (int r = 0; r < 4; r++)
    #pragma unroll
    for (int c = 0; c < 4; c++)
      wreg[r][c] = *(const v4f*)(Whh + (size_t)(rw + r) * HID + c * 256 + 4 * lane);

  float u_cur = U[myrow];   // step-0 input

  // prologue: wave 0 polls slot 0 (row 0, base 2.0) into hsh[0]
  if (w == 0) poll_relay(hbuf, 2.0f, hsh[0], lane, &sdead);
  __syncthreads();

  #pragma unroll 1
  for (int t = 0; t < SEQ; t++) {
    if (sdead) break;   // uniform after the preceding barrier

    // consume relayed h (raw, de-biased) — conflict-free ds_read_b128
    const float* hp = hsh[t & 1];
    v4f hd0 = *(const v4f*)(hp +   0 + 4 * lane);
    v4f hd1 = *(const v4f*)(hp + 256 + 4 * lane);
    v4f hd2 = *(const v4f*)(hp + 512 + 4 * lane);
    v4f hd3 = *(const v4f*)(hp + 768 + 4 * lane);

    float a[4];
    #pragma unroll
    for (int r = 0; r < 4; r++) {
      a[r] = wreg[r][0].x*hd0.x + wreg[r][0].y*hd0.y + wreg[r][0].z*hd0.z + wreg[r][0].w*hd0.w
           + wreg[r][1].x*hd1.x + wreg[r][1].y*hd1.y + wreg[r][1].z*hd1.z + wreg[r][1].w*hd1.w
           + wreg[r][2].x*hd2.x + wreg[r][2].y*hd2.y + wreg[r][2].z*hd2.z + wreg[r][2].w*hd2.w
           + wreg[r][3].x*hd3.x + wreg[r][3].y*hd3.y + wreg[r][3].z*hd3.z + wreg[r][3].w*hd3.w;
    }

    // butterfly reduce across 64 lanes (4 interleaved chains)
    #pragma unroll
    for (int m = 1; m <= 32; m <<= 1) {
      a[0] += __shfl_xor(a[0], m);
      a[1] += __shfl_xor(a[1], m);
      a[2] += __shfl_xor(a[2], m);
      a[3] += __shfl_xor(a[3], m);
    }

    // lane l (0..3) finalizes row rw + l
    float y01 = (lane & 1) ? a[1] : a[0];
    float y23 = (lane & 1) ? a[3] : a[2];
    float y   = (lane & 2) ? y23 : y01;
    const float hn = tanh_fast(y + u_cur);

    const float Bp = 2.0f + 4.0f * (float)(((t + 1) >> 2) & 1);
    if (lane < 4) {
      float tv = hn + Bp;
      const float* dst = hbuf + (((t + 1) & 3) << 10) + rw + lane;
      asm volatile("global_store_dword %0, %1, off sc0 sc1"
                   :: "v"(dst), "v"(tv) : "memory");
      out[(size_t)(t + 1) * HID + rw + lane] = hn;   // raw output
      // fire-and-forget: no dest regs; drained inside the next poll's waits.
    }

    // prefetch next step's U row (h-independent)
    float u_next = U[(size_t)((t + 1 < SEQ) ? t + 1 : t) * HID + myrow];

    // wave 0: poll next row into the other LDS buffer (after own publish)
    if (w == 0 && t + 1 < SEQ)
      poll_relay(hbuf + (((t + 1) & 3) << 10), Bp, hsh[(t + 1) & 1], lane, &sdead);

    __syncthreads();   // relay visible to all; doubles as WAR guard on hsh
    u_cur = u_next;
  }
}

// ---------------------------------------------------------------------------
extern "C" void kernel_launch(void* const* d_in, const int* in_sizes, int n_in,
                              void* d_out, int out_size, void* d_ws, size_t ws_size,
                              hipStream_t stream) {
  const int*   src = (const int*)  d_in[0];
  const float* W   = (const float*)d_in[1];
  const float* h0  = (const float*)d_in[2];
  const float* Whi = (const float*)d_in[3];
  const float* Whh = (const float*)d_in[4];
  const float* b   = (const float*)d_in[5];
  float* out = (float*)d_out;

  float* U    = (float*)d_ws;                                              // 16 MB
  float* hbuf = (float*)((char*)d_ws + (size_t)SEQ * HID * sizeof(float)); // 16 KB, 4 slots
  // d_ws re-poisoned to 0xAA before every launch: poison fails every tag
  // window, so no memset and no cross-replay staleness.

  embed_gemm<<<SEQ / BT, 256, 0, stream>>>(src, W, Whi, b, U);
  rnn_seq<<<NWG, 256, 0, stream>>>(Whh, U, h0, out, hbuf);
}